// Round 1
// 854.251 us; speedup vs baseline: 1.7703x; 1.7703x over previous
//
#include <hip/hip_runtime.h>

#define D256 256
#define ALEN 128
#define INDIM 512
#define BSZ 32
#define TLEN 2048
#define CHL 32     // chunk length
#define NCH 64     // number of chunks

typedef __attribute__((ext_vector_type(8))) short short8;  // 8 x bf16
typedef __attribute__((ext_vector_type(4))) float f32x4;

__device__ __forceinline__ float leakyf(float x)  { return x < 0.f ? 0.01f * x : x; }
__device__ __forceinline__ float ileakyf(float x) { return x < 0.f ? x * 100.0f : x; }

__device__ __forceinline__ unsigned short f2bf(float f) {
  unsigned int x = __float_as_uint(f);
  unsigned int r = x + 0x7FFFu + ((x >> 16) & 1u);  // RNE
  return (unsigned short)(r >> 16);
}

__device__ __forceinline__ void gload16(const void* g, const void* l) {
  __builtin_amdgcn_global_load_lds(
      (const __attribute__((address_space(1))) unsigned int*)g,
      (__attribute__((address_space(3))) unsigned int*)l, 16, 0, 0);
}

// cross-lane adds for the 8-way d-group reduction (dg = lane & 7)
template <int CTRL>
__device__ __forceinline__ float dpp_addf(float x) {
  return x + __int_as_float(__builtin_amdgcn_update_dpp(
                 0, __float_as_int(x), CTRL, 0xF, 0xF, true));
}
__device__ __forceinline__ float swz4_addf(float x) {
  // ds_swizzle xor-4: offset = (4<<10) | 0x1F
  return x + __int_as_float(
                 __builtin_amdgcn_ds_swizzle(__float_as_int(x), 0x101F));
}

// ---------------------------------------------------------------------------
// bf16 MFMA GEMM (m97 structure): Out[m][n] = sum_k In[m][k]*W[n][k]
// (+bias1[n]+bias2[n], optional inv_leaky). 128x128 tile, BK=32, 4 waves.
// ---------------------------------------------------------------------------
__global__ __launch_bounds__(256) void gemm_mfma(
    const unsigned short* __restrict__ In, int K,
    const unsigned short* __restrict__ W,
    const float* __restrict__ bias1, const float* __restrict__ bias2,
    int ileaky_act, int out_bf16, void* __restrict__ Outp) {
  __shared__ char lds[16384];  // A tile 8KB @0, B tile 8KB @8192
  const int tid = threadIdx.x;
  const int lane = tid & 63, w = tid >> 6;
  const int m0 = blockIdx.x * 128, n0 = blockIdx.y * 128;
  const int wm = (w & 1) * 64, wn = (w >> 1) * 64;
  const int quad = lane >> 4, l16 = lane & 15;

  f32x4 acc[4][4];
#pragma unroll
  for (int i = 0; i < 4; ++i)
#pragma unroll
    for (int j = 0; j < 4; ++j) acc[i][j] = {0.f, 0.f, 0.f, 0.f};

  for (int kb = 0; kb < K; kb += 32) {
    __syncthreads();
#pragma unroll
    for (int q = 0; q < 2; ++q) {
      const int id = (w * 2 + q) * 64 + lane;
      const int row = id >> 2, ch = id & 3;
      gload16(In + (size_t)(m0 + row) * K + kb + ch * 8,
              lds + (w * 2 + q) * 1024);
      gload16(W + (size_t)(n0 + row) * K + kb + ch * 8,
              lds + 8192 + (w * 2 + q) * 1024);
    }
    __syncthreads();

    short8 af[4], bf[4];
#pragma unroll
    for (int i = 0; i < 4; ++i) {
      af[i] = *(const short8*)(lds + ((wm + i * 16 + l16) * 64 + quad * 16));
      bf[i] = *(const short8*)(lds + 8192 + ((wn + i * 16 + l16) * 64 + quad * 16));
    }
#pragma unroll
    for (int i = 0; i < 4; ++i)
#pragma unroll
      for (int j = 0; j < 4; ++j)
        acc[i][j] = __builtin_amdgcn_mfma_f32_16x16x32_bf16(af[i], bf[j], acc[i][j], 0, 0, 0);
  }

#pragma unroll
  for (int j = 0; j < 4; ++j) {
    const int n = n0 + wn + j * 16 + l16;
    const float bv = (bias1 ? bias1[n] : 0.f) + (bias2 ? bias2[n] : 0.f);
#pragma unroll
    for (int i = 0; i < 4; ++i) {
#pragma unroll
      for (int r = 0; r < 4; ++r) {
        const int m = m0 + wm + i * 16 + quad * 4 + r;
        float v = acc[i][j][r] + bv;
        if (ileaky_act) v = ileakyf(v);
        if (out_bf16)
          ((unsigned short*)Outp)[(size_t)m * 256 + n] = f2bf(v);
        else
          ((float*)Outp)[(size_t)m * 256 + n] = v;
      }
    }
  }
}

// ---------------------------------------------------------------------------
// fp32 squaring GEMM for A-power chain: given (X, X^T) emit (X^2, (X^2)^T).
// Out[m][n] = sum_k X[m][k] * XT[n][k]  = X@X.  64x64 tile, 4x4 micro.
// ---------------------------------------------------------------------------
__global__ __launch_bounds__(256) void gemm_sq(
    const float* __restrict__ X, const float* __restrict__ XT,
    float* __restrict__ Out, float* __restrict__ OutT) {
  __shared__ float a_lds[64][40];
  __shared__ float b_lds[64][40];
  const int tid = threadIdx.x;
  const int tm = tid >> 4, tn = tid & 15;
  const int m0 = blockIdx.x * 64, n0 = blockIdx.y * 64;
  float acc[4][4];
#pragma unroll
  for (int i = 0; i < 4; ++i)
#pragma unroll
    for (int j = 0; j < 4; ++j) acc[i][j] = 0.f;

  for (int kb = 0; kb < 256; kb += 32) {
    __syncthreads();
#pragma unroll
    for (int q = 0; q < 2; ++q) {
      const int slot = q * 256 + tid;
      const int row = slot >> 3, s4 = slot & 7;
      *(float4*)&a_lds[row][s4 * 4] = *(const float4*)&X[(size_t)(m0 + row) * 256 + kb + s4 * 4];
      *(float4*)&b_lds[row][s4 * 4] = *(const float4*)&XT[(size_t)(n0 + row) * 256 + kb + s4 * 4];
    }
    __syncthreads();
#pragma unroll
    for (int k4 = 0; k4 < 8; ++k4) {
      float4 a4[4], b4[4];
#pragma unroll
      for (int i = 0; i < 4; ++i) a4[i] = *(const float4*)&a_lds[tm * 4 + i][k4 * 4];
#pragma unroll
      for (int j = 0; j < 4; ++j) b4[j] = *(const float4*)&b_lds[tn * 4 + j][k4 * 4];
#pragma unroll
      for (int i = 0; i < 4; ++i)
#pragma unroll
        for (int j = 0; j < 4; ++j)
          acc[i][j] += a4[i].x * b4[j].x + a4[i].y * b4[j].y +
                       a4[i].z * b4[j].z + a4[i].w * b4[j].w;
    }
  }
#pragma unroll
  for (int i = 0; i < 4; ++i) {
    const int m = m0 + tm * 4 + i;
    *(float4*)&Out[(size_t)m * 256 + n0 + tn * 4] =
        make_float4(acc[i][0], acc[i][1], acc[i][2], acc[i][3]);
#pragma unroll
    for (int j = 0; j < 4; ++j)
      OutT[(size_t)(n0 + tn * 4 + j) * 256 + m] = acc[i][j];
  }
}

// ---------------------------------------------------------------------------
// 256x256 transpose (out[d][e] = in[e][d]) — feeds the gemm_sq power chain
// ---------------------------------------------------------------------------
__global__ __launch_bounds__(256) void transpose256(const float* __restrict__ in,
                                                    float* __restrict__ out) {
  __shared__ float t[32][33];
  const int lx = threadIdx.x, ly = threadIdx.y;
  const int bx = blockIdx.x * 32, by = blockIdx.y * 32;
#pragma unroll
  for (int i = 0; i < 4; ++i)
    t[ly + 8 * i][lx] = in[(size_t)(by + ly + 8 * i) * 256 + bx + lx];
  __syncthreads();
#pragma unroll
  for (int i = 0; i < 4; ++i)
    out[(size_t)(bx + ly + 8 * i) * 256 + by + lx] = t[lx][ly + 8 * i];
}

// ---------------------------------------------------------------------------
// Encoder, t=0 only
// ---------------------------------------------------------------------------
__global__ __launch_bounds__(256) void encoder_kernel(
    const float* __restrict__ in, const float* __restrict__ We1,
    const float* __restrict__ be1, const float* __restrict__ We2,
    const float* __restrict__ be2, float* __restrict__ z0) {
  const int b = blockIdx.x, e = threadIdx.x;
  __shared__ float xb[256];
  __shared__ float h1[256];
  xb[e] = in[(size_t)b * TLEN * INDIM + e];
  __syncthreads();
  float acc = be1[e];
  const float4* w = (const float4*)(We1 + (size_t)e * 256);
#pragma unroll 8
  for (int d4 = 0; d4 < 64; ++d4) {
    float4 wv = w[d4];
    acc += wv.x * xb[4 * d4] + wv.y * xb[4 * d4 + 1] + wv.z * xb[4 * d4 + 2] + wv.w * xb[4 * d4 + 3];
  }
  h1[e] = leakyf(acc);
  __syncthreads();
  float a2 = be2[e];
  w = (const float4*)(We2 + (size_t)e * 256);
#pragma unroll 8
  for (int d4 = 0; d4 < 64; ++d4) {
    float4 wv = w[d4];
    a2 += wv.x * h1[4 * d4] + wv.y * h1[4 * d4 + 1] + wv.z * h1[4 * d4 + 2] + wv.w * h1[4 * d4 + 3];
  }
  z0[(size_t)b * 256 + e] = leakyf(a2);
}

// ---------------------------------------------------------------------------
// extract u columns -> dense bf16 [65536][128]; needs 8192 blocks (R2 bug).
// ---------------------------------------------------------------------------
__global__ __launch_bounds__(256) void extract_u(const float* __restrict__ in,
                                                 unsigned short* __restrict__ ubuf) {
  const int gid = blockIdx.x * 256 + threadIdx.x;
  const int row = gid >> 5;
  const int c = (gid & 31) * 4;
  float4 v = *(const float4*)&in[(size_t)row * INDIM + 256 + c];
  *(ushort4*)&ubuf[(size_t)row * 128 + c] =
      make_ushort4(f2bf(v.x), f2bf(v.y), f2bf(v.z), f2bf(v.w));
}

__global__ __launch_bounds__(256) void f2bf_kernel(const float* __restrict__ in,
                                                   unsigned short* __restrict__ out, int n) {
  const int i4 = blockIdx.x * 256 + threadIdx.x;
  if (i4 * 4 < n) {
    float4 v = *(const float4*)&in[(size_t)i4 * 4];
    *(ushort4*)&out[(size_t)i4 * 4] = make_ushort4(f2bf(v.x), f2bf(v.y), f2bf(v.z), f2bf(v.w));
  }
}

// ---------------------------------------------------------------------------
// Chunked-scan phase kernel v3 (fp32): A cached in REGISTERS.
// v2 was L1-return-BW bound: every step re-streamed the 256KB A^T with 8x
// lane duplication (~2 MB/block/step through L1 -> ~32K cyc/step). v3 loads
// A once into VGPRs (thread (w,lane) owns e-quad [w*32+le*4, +4) x d-slice
// [dg*32, +32), dg=lane&7, le=lane>>3 -> 512 threads x 128 regs = 64K = A,
// zero replication). Per step only the 8-rho carry (8 KB) moves through LDS
// (bank-conflict-free: 36-word dg stride) and the 8-way d-partial reduce is
// in-register: DPP quad-perm xor1/xor2 + ds_swizzle xor4. Thread is the
// owner/writer of rho=dg at its e-quad -> C-load, carry write, w1 store all
// run with 64/64 lanes active.
// ---------------------------------------------------------------------------
__global__ __launch_bounds__(512, 2) void phase_kernel(
    const float* __restrict__ AW, const float* __restrict__ Cbuf,
    const float* __restrict__ Einit, float* __restrict__ Lend,
    unsigned short* __restrict__ w1out) {
  const int tid = threadIdx.x;
  const int w = tid >> 6;
  const int lane = tid & 63;
  const int dg = lane & 7;        // d-group: owns d in [dg*32, dg*32+32)
  const int le = lane >> 3;       // e-quad within wave's 32-e slice
  const int e0 = w * 32 + le * 4;
  const int d0 = dg * 32;
  const int rho0 = blockIdx.x << 3;
  const int k = rho0 >> 5;
  const int b = (rho0 & 31) + dg;   // owned rho's batch index
  const int rho = rho0 + dg;        // owned rho (rho = k*32 + b)

  // carry[buf][rho][pd(d)], pd(d) = d + (d>>5)*4 : d-group stride 36 words so
  // the 8 dg lanes of a read land on 8 distinct 4-bank groups (32 banks).
  __shared__ __align__(16) float carry[2][8][288];

  // ---- load this thread's A tile into registers (once) ----
  float4 Ar[4][8];
#pragma unroll
  for (int i = 0; i < 4; ++i)
#pragma unroll
    for (int k4 = 0; k4 < 8; ++k4)
      Ar[i][k4] = *(const float4*)&AW[(size_t)(e0 + i) * 256 + d0 + k4 * 4];

  // ---- init carry[0]: thread initializes its owned (rho=dg, e-quad) ----
  float4 cur;
  if (Einit) cur = *(const float4*)&Einit[(size_t)rho * 256 + e0];
  else       cur = make_float4(0.f, 0.f, 0.f, 0.f);
  const int epad = e0 + ((e0 >> 5) << 2);   // = w*36 + le*4
  *(float4*)&carry[0][dg][epad] = cur;
  __syncthreads();

  const float4* crow = (const float4*)(Cbuf + ((size_t)b * TLEN + (size_t)k * CHL) * 256 + e0);
  ushort4* wrow = w1out
      ? (ushort4*)(w1out + ((size_t)b * TLEN + (size_t)k * CHL) * 256 + e0)
      : (ushort4*)0;

  int buf = 0;
  for (int j = 0; j < CHL; ++j) {
    float4 cj = *crow;  // independent of carry: latency hides under the FMAs
    crow += 64;
    float4 nxt = make_float4(0.f, 0.f, 0.f, 0.f);
#pragma unroll
    for (int r = 0; r < 8; ++r) {
      float4 s = make_float4(0.f, 0.f, 0.f, 0.f);
#pragma unroll
      for (int k4 = 0; k4 < 8; ++k4) {
        const float4 cv = *(const float4*)&carry[buf][r][dg * 36 + k4 * 4];
        s.x += Ar[0][k4].x * cv.x + Ar[0][k4].y * cv.y + Ar[0][k4].z * cv.z + Ar[0][k4].w * cv.w;
        s.y += Ar[1][k4].x * cv.x + Ar[1][k4].y * cv.y + Ar[1][k4].z * cv.z + Ar[1][k4].w * cv.w;
        s.z += Ar[2][k4].x * cv.x + Ar[2][k4].y * cv.y + Ar[2][k4].z * cv.z + Ar[2][k4].w * cv.w;
        s.w += Ar[3][k4].x * cv.x + Ar[3][k4].y * cv.y + Ar[3][k4].z * cv.z + Ar[3][k4].w * cv.w;
      }
      // reduce across the 8 d-groups (lane bits 0..2): all lanes end with sum
      s.x = dpp_addf<0xB1>(s.x); s.y = dpp_addf<0xB1>(s.y);
      s.z = dpp_addf<0xB1>(s.z); s.w = dpp_addf<0xB1>(s.w);   // xor 1
      s.x = dpp_addf<0x4E>(s.x); s.y = dpp_addf<0x4E>(s.y);
      s.z = dpp_addf<0x4E>(s.z); s.w = dpp_addf<0x4E>(s.w);   // xor 2
      s.x = swz4_addf(s.x); s.y = swz4_addf(s.y);
      s.z = swz4_addf(s.z); s.w = swz4_addf(s.w);             // xor 4
      if (dg == r) nxt = s;   // stash the rho this thread owns
    }
    cur = make_float4(nxt.x + cj.x, nxt.y + cj.y, nxt.z + cj.z, nxt.w + cj.w);
    buf ^= 1;
    *(float4*)&carry[buf][dg][epad] = cur;
    if (w1out) {
      *wrow = make_ushort4(f2bf(ileakyf(cur.x)), f2bf(ileakyf(cur.y)),
                           f2bf(ileakyf(cur.z)), f2bf(ileakyf(cur.w)));
      wrow += 64;
    }
    __syncthreads();
  }
  if (Lend) *(float4*)&Lend[(size_t)rho * 256 + e0] = cur;
}

// ---------------------------------------------------------------------------
// Boundary recurrence v2: E[k+1] = P*E[k] + Lend[k]. 512 threads: wave w owns
// e-slice, lane-group r owns d-slice [r*32, r*32+32); LDS tree-reduce over r.
// ---------------------------------------------------------------------------
__global__ __launch_bounds__(512, 2) void boundary_kernel(
    const float* __restrict__ PT, const float* __restrict__ z0,
    const float* __restrict__ Lend, float* __restrict__ Earr) {
  const int tid = threadIdx.x;
  const int w = tid >> 6;
  const int l = tid & 63;
  const int r = l >> 3;
  const int le = l & 7;
  const int e0 = w * 32 + le * 4;
  const int b = blockIdx.x;
  __shared__ float Ec[256];
  __shared__ float part[8][260];

  if (tid < 256) Ec[tid] = z0[(size_t)b * 256 + tid];
  __syncthreads();

  for (int k = 0; k < NCH; ++k) {
    if (tid < 256) Earr[((size_t)k * BSZ + b) * 256 + tid] = Ec[tid];
    float4 acc = make_float4(0.f, 0.f, 0.f, 0.f);
    const float* Pbase = PT + (size_t)(r * 32) * 256 + e0;
#pragma unroll 2
    for (int d4 = 0; d4 < 8; ++d4) {
      const float4 cv = *(const float4*)&Ec[r * 32 + d4 * 4];
      const float* ap = Pbase + (size_t)d4 * 1024;
      const float4 a0 = *(const float4*)(ap);
      const float4 a1 = *(const float4*)(ap + 256);
      const float4 a2 = *(const float4*)(ap + 512);
      const float4 a3 = *(const float4*)(ap + 768);
      acc.x += a0.x * cv.x + a1.x * cv.y + a2.x * cv.z + a3.x * cv.w;
      acc.y += a0.y * cv.x + a1.y * cv.y + a2.y * cv.z + a3.y * cv.w;
      acc.z += a0.z * cv.x + a1.z * cv.y + a2.z * cv.z + a3.z * cv.w;
      acc.w += a0.w * cv.x + a1.w * cv.y + a2.w * cv.z + a3.w * cv.w;
    }
    *(float4*)&part[r][e0] = acc;
    __syncthreads();               // part complete; all Ec reads done
    float s = 0.f;
    if (tid < 256) {
      s = Lend[((size_t)k * BSZ + b) * 256 + tid];
#pragma unroll
      for (int rr = 0; rr < 8; ++rr) s += part[rr][tid];
    }
    __syncthreads();               // part reads done before next overwrite
    if (tid < 256) Ec[tid] = s;
    __syncthreads();               // new Ec visible
  }
}

// ---------------------------------------------------------------------------
extern "C" void kernel_launch(void* const* d_in, const int* in_sizes, int n_in,
                              void* d_out, int out_size, void* d_ws, size_t ws_size,
                              hipStream_t stream) {
  const float* in  = (const float*)d_in[0];
  const float* We1 = (const float*)d_in[1];
  const float* be1 = (const float*)d_in[2];
  const float* We2 = (const float*)d_in[3];
  const float* be2 = (const float*)d_in[4];
  const float* A_W = (const float*)d_in[5];
  const float* A_b = (const float*)d_in[6];
  const float* B_W = (const float*)d_in[7];
  const float* B_b = (const float*)d_in[8];
  const float* Wd1 = (const float*)d_in[9];
  const float* bd1 = (const float*)d_in[10];
  const float* Wd2 = (const float*)d_in[11];
  const float* bd2 = (const float*)d_in[12];
  float* out = (float*)d_out;

  float* ws   = (float*)d_ws;
  float* Cbuf = ws;                    // 16,777,216 f
  float* AT   = Cbuf + 16777216;       // 65,536
  float* PT   = AT + 65536;            // 65,536
  float* Pa   = PT + 65536;            // 65,536
  float* PaT  = Pa + 65536;            // 65,536
  float* Pb   = PaT + 65536;           // 65,536
  float* PbT  = Pb + 65536;            // 65,536
  float* z0   = PbT + 65536;           // 8,192
  float* Lend = z0 + 8192;             // 524,288
  float* Earr = Lend + 524288;         // 524,288
  unsigned short* BWb  = (unsigned short*)(Earr + 524288);  // 32,768 us
  unsigned short* Wd1b = BWb + 32768;                       // 65,536 us
  unsigned short* Wd2b = Wd1b + 65536;                      // 65,536 us

  // d_out staging: [0,16MB) ubuf bf16; [16MB,48MB) w1 bf16; final fp32 overwrites
  unsigned short* ubuf = (unsigned short*)d_out;            // 65536x128 bf16
  unsigned short* w1   = ubuf + 8388608;                    // 65536x256 bf16
  unsigned short* w2   = (unsigned short*)Cbuf;             // 65536x256 bf16 (Cbuf dead after phase3)

  const dim3 tblk(32, 8), tgrid(8, 8);

  transpose256<<<tgrid, tblk, 0, stream>>>(A_W, AT);
  encoder_kernel<<<32, 256, 0, stream>>>(in, We1, be1, We2, be2, z0);
  extract_u<<<8192, 256, 0, stream>>>(in, ubuf);
  f2bf_kernel<<<32, 256, 0, stream>>>(B_W, BWb, 32768);
  f2bf_kernel<<<64, 256, 0, stream>>>(Wd1, Wd1b, 65536);
  f2bf_kernel<<<64, 256, 0, stream>>>(Wd2, Wd2b, 65536);

  // c_t = u @ B_W^T + B_b + A_b -> Cbuf (fp32)
  gemm_mfma<<<dim3(512, 2), 256, 0, stream>>>(ubuf, ALEN, BWb, A_b, B_b, 0, 0, Cbuf);

  // P = A^32 by repeated squaring, dual-output (X^2, (X^2)^T) per launch
  gemm_sq<<<dim3(4, 4), 256, 0, stream>>>(A_W, AT, Pa, PaT);   // A^2
  gemm_sq<<<dim3(4, 4), 256, 0, stream>>>(Pa, PaT, Pb, PbT);   // A^4
  gemm_sq<<<dim3(4, 4), 256, 0, stream>>>(Pb, PbT, Pa, PaT);   // A^8
  gemm_sq<<<dim3(4, 4), 256, 0, stream>>>(Pa, PaT, Pb, PbT);   // A^16
  gemm_sq<<<dim3(4, 4), 256, 0, stream>>>(Pb, PbT, Pa, PT);    // A^32; PT = (A^32)^T

  phase_kernel<<<256, 512, 0, stream>>>(A_W, Cbuf, nullptr, Lend, nullptr);
  boundary_kernel<<<32, 512, 0, stream>>>(PT, z0, Lend, Earr);
  phase_kernel<<<256, 512, 0, stream>>>(A_W, Cbuf, Earr, nullptr, w1);

  // dec1: w2 = bf16(inv_leaky(w1 @ Wd1^T + bd1))
  gemm_mfma<<<dim3(512, 2), 256, 0, stream>>>(w1, D256, Wd1b, bd1, nullptr, 1, 1, w2);
  // dec2: y = w2 @ Wd2^T + bd2 -> d_out (fp32)
  gemm_mfma<<<dim3(512, 2), 256, 0, stream>>>(w2, D256, Wd2b, bd2, nullptr, 0, 0, out);
}

// Round 2
// 754.920 us; speedup vs baseline: 2.0032x; 1.1316x over previous
//
#include <hip/hip_runtime.h>

#define D256 256
#define ALEN 128
#define INDIM 512
#define BSZ 32
#define TLEN 2048
#define CHL 32     // chunk length
#define NCH 64     // number of chunks

typedef __attribute__((ext_vector_type(8))) short short8;  // 8 x bf16
typedef __attribute__((ext_vector_type(4))) float f32x4;

__device__ __forceinline__ float leakyf(float x)  { return x < 0.f ? 0.01f * x : x; }
__device__ __forceinline__ float ileakyf(float x) { return x < 0.f ? x * 100.0f : x; }

__device__ __forceinline__ unsigned short f2bf(float f) {
  unsigned int x = __float_as_uint(f);
  unsigned int r = x + 0x7FFFu + ((x >> 16) & 1u);  // RNE
  return (unsigned short)(r >> 16);
}

__device__ __forceinline__ void gload16(const void* g, const void* l) {
  __builtin_amdgcn_global_load_lds(
      (const __attribute__((address_space(1))) unsigned int*)g,
      (__attribute__((address_space(3))) unsigned int*)l, 16, 0, 0);
}

// cross-lane adds for the 8-way d-group reduction (dg = lane & 7).
// xor1 = quad_perm 0xB1, xor2 = quad_perm 0x4E, final stage = row_half_mirror
// (0x141): after xor1/xor2 each 4-aligned quad is uniform, so mirroring the
// 8-lane half pairs the two quad-sums -> full 8-sum on every lane, no LDS.
template <int CTRL>
__device__ __forceinline__ float dpp_addf(float x) {
  return x + __int_as_float(__builtin_amdgcn_update_dpp(
                 0, __float_as_int(x), CTRL, 0xF, 0xF, true));
}
__device__ __forceinline__ void red8(float4& s) {
  s.x = dpp_addf<0xB1>(s.x); s.y = dpp_addf<0xB1>(s.y);
  s.z = dpp_addf<0xB1>(s.z); s.w = dpp_addf<0xB1>(s.w);   // xor 1
  s.x = dpp_addf<0x4E>(s.x); s.y = dpp_addf<0x4E>(s.y);
  s.z = dpp_addf<0x4E>(s.z); s.w = dpp_addf<0x4E>(s.w);   // xor 2
  s.x = dpp_addf<0x141>(s.x); s.y = dpp_addf<0x141>(s.y);
  s.z = dpp_addf<0x141>(s.z); s.w = dpp_addf<0x141>(s.w); // half-mirror (xor 4-equiv)
}

// ---------------------------------------------------------------------------
// bf16 MFMA GEMM (m97 structure): Out[m][n] = sum_k In[m][k]*W[n][k]
// (+bias1[n]+bias2[n], optional inv_leaky). 128x128 tile, BK=32, 4 waves.
// ---------------------------------------------------------------------------
__global__ __launch_bounds__(256) void gemm_mfma(
    const unsigned short* __restrict__ In, int K,
    const unsigned short* __restrict__ W,
    const float* __restrict__ bias1, const float* __restrict__ bias2,
    int ileaky_act, int out_bf16, void* __restrict__ Outp) {
  __shared__ char lds[16384];  // A tile 8KB @0, B tile 8KB @8192
  const int tid = threadIdx.x;
  const int lane = tid & 63, w = tid >> 6;
  const int m0 = blockIdx.x * 128, n0 = blockIdx.y * 128;
  const int wm = (w & 1) * 64, wn = (w >> 1) * 64;
  const int quad = lane >> 4, l16 = lane & 15;

  f32x4 acc[4][4];
#pragma unroll
  for (int i = 0; i < 4; ++i)
#pragma unroll
    for (int j = 0; j < 4; ++j) acc[i][j] = {0.f, 0.f, 0.f, 0.f};

  for (int kb = 0; kb < K; kb += 32) {
    __syncthreads();
#pragma unroll
    for (int q = 0; q < 2; ++q) {
      const int id = (w * 2 + q) * 64 + lane;
      const int row = id >> 2, ch = id & 3;
      gload16(In + (size_t)(m0 + row) * K + kb + ch * 8,
              lds + (w * 2 + q) * 1024);
      gload16(W + (size_t)(n0 + row) * K + kb + ch * 8,
              lds + 8192 + (w * 2 + q) * 1024);
    }
    __syncthreads();

    short8 af[4], bf[4];
#pragma unroll
    for (int i = 0; i < 4; ++i) {
      af[i] = *(const short8*)(lds + ((wm + i * 16 + l16) * 64 + quad * 16));
      bf[i] = *(const short8*)(lds + 8192 + ((wn + i * 16 + l16) * 64 + quad * 16));
    }
#pragma unroll
    for (int i = 0; i < 4; ++i)
#pragma unroll
      for (int j = 0; j < 4; ++j)
        acc[i][j] = __builtin_amdgcn_mfma_f32_16x16x32_bf16(af[i], bf[j], acc[i][j], 0, 0, 0);
  }

#pragma unroll
  for (int j = 0; j < 4; ++j) {
    const int n = n0 + wn + j * 16 + l16;
    const float bv = (bias1 ? bias1[n] : 0.f) + (bias2 ? bias2[n] : 0.f);
#pragma unroll
    for (int i = 0; i < 4; ++i) {
#pragma unroll
      for (int r = 0; r < 4; ++r) {
        const int m = m0 + wm + i * 16 + quad * 4 + r;
        float v = acc[i][j][r] + bv;
        if (ileaky_act) v = ileakyf(v);
        if (out_bf16)
          ((unsigned short*)Outp)[(size_t)m * 256 + n] = f2bf(v);
        else
          ((float*)Outp)[(size_t)m * 256 + n] = v;
      }
    }
  }
}

// ---------------------------------------------------------------------------
// fp32 squaring GEMM for A-power chain: given (X, X^T) emit (X^2, (X^2)^T).
// Out[m][n] = sum_k X[m][k] * XT[n][k]  = X@X.  64x64 tile, 4x4 micro.
// ---------------------------------------------------------------------------
__global__ __launch_bounds__(256) void gemm_sq(
    const float* __restrict__ X, const float* __restrict__ XT,
    float* __restrict__ Out, float* __restrict__ OutT) {
  __shared__ float a_lds[64][40];
  __shared__ float b_lds[64][40];
  const int tid = threadIdx.x;
  const int tm = tid >> 4, tn = tid & 15;
  const int m0 = blockIdx.x * 64, n0 = blockIdx.y * 64;
  float acc[4][4];
#pragma unroll
  for (int i = 0; i < 4; ++i)
#pragma unroll
    for (int j = 0; j < 4; ++j) acc[i][j] = 0.f;

  for (int kb = 0; kb < 256; kb += 32) {
    __syncthreads();
#pragma unroll
    for (int q = 0; q < 2; ++q) {
      const int slot = q * 256 + tid;
      const int row = slot >> 3, s4 = slot & 7;
      *(float4*)&a_lds[row][s4 * 4] = *(const float4*)&X[(size_t)(m0 + row) * 256 + kb + s4 * 4];
      *(float4*)&b_lds[row][s4 * 4] = *(const float4*)&XT[(size_t)(n0 + row) * 256 + kb + s4 * 4];
    }
    __syncthreads();
#pragma unroll
    for (int k4 = 0; k4 < 8; ++k4) {
      float4 a4[4], b4[4];
#pragma unroll
      for (int i = 0; i < 4; ++i) a4[i] = *(const float4*)&a_lds[tm * 4 + i][k4 * 4];
#pragma unroll
      for (int j = 0; j < 4; ++j) b4[j] = *(const float4*)&b_lds[tn * 4 + j][k4 * 4];
#pragma unroll
      for (int i = 0; i < 4; ++i)
#pragma unroll
        for (int j = 0; j < 4; ++j)
          acc[i][j] += a4[i].x * b4[j].x + a4[i].y * b4[j].y +
                       a4[i].z * b4[j].z + a4[i].w * b4[j].w;
    }
  }
#pragma unroll
  for (int i = 0; i < 4; ++i) {
    const int m = m0 + tm * 4 + i;
    *(float4*)&Out[(size_t)m * 256 + n0 + tn * 4] =
        make_float4(acc[i][0], acc[i][1], acc[i][2], acc[i][3]);
#pragma unroll
    for (int j = 0; j < 4; ++j)
      OutT[(size_t)(n0 + tn * 4 + j) * 256 + m] = acc[i][j];
  }
}

// ---------------------------------------------------------------------------
// Fused prep: transpose(A_W)->AT (blocks 0..63), encoder t=0 (64..95),
// f2bf B_W (96..127), Wd1 (128..191), Wd2 (192..255). One launch, 256 blocks.
// ---------------------------------------------------------------------------
__global__ __launch_bounds__(256) void prep_kernel(
    const float* __restrict__ in, const float* __restrict__ We1,
    const float* __restrict__ be1, const float* __restrict__ We2,
    const float* __restrict__ be2, const float* __restrict__ A_W,
    const float* __restrict__ B_W, const float* __restrict__ Wd1,
    const float* __restrict__ Wd2, float* __restrict__ AT,
    float* __restrict__ z0, unsigned short* __restrict__ BWb,
    unsigned short* __restrict__ Wd1b, unsigned short* __restrict__ Wd2b) {
  __shared__ float sm[1056];
  const int tid = threadIdx.x;
  const int blk = blockIdx.x;
  if (blk < 64) {
    // A_W -> AT transpose (32x32 tile)
    const int bx = (blk & 7) * 32, by = (blk >> 3) * 32;
    const int lx = tid & 31, ly = tid >> 5;
#pragma unroll
    for (int i = 0; i < 4; ++i)
      sm[(ly + 8 * i) * 33 + lx] = A_W[(size_t)(by + ly + 8 * i) * 256 + bx + lx];
    __syncthreads();
#pragma unroll
    for (int i = 0; i < 4; ++i)
      AT[(size_t)(bx + ly + 8 * i) * 256 + by + lx] = sm[lx * 33 + ly + 8 * i];
  } else if (blk < 96) {
    // encoder, t=0 only
    const int b = blk - 64, e = tid;
    float* xb = sm;
    float* h1 = sm + 256;
    xb[e] = in[(size_t)b * TLEN * INDIM + e];
    __syncthreads();
    float acc = be1[e];
    const float4* w = (const float4*)(We1 + (size_t)e * 256);
#pragma unroll 8
    for (int d4 = 0; d4 < 64; ++d4) {
      float4 wv = w[d4];
      acc += wv.x * xb[4 * d4] + wv.y * xb[4 * d4 + 1] + wv.z * xb[4 * d4 + 2] + wv.w * xb[4 * d4 + 3];
    }
    h1[e] = leakyf(acc);
    __syncthreads();
    float a2 = be2[e];
    w = (const float4*)(We2 + (size_t)e * 256);
#pragma unroll 8
    for (int d4 = 0; d4 < 64; ++d4) {
      float4 wv = w[d4];
      a2 += wv.x * h1[4 * d4] + wv.y * h1[4 * d4 + 1] + wv.z * h1[4 * d4 + 2] + wv.w * h1[4 * d4 + 3];
    }
    z0[(size_t)b * 256 + e] = leakyf(a2);
  } else {
    const float* src;
    unsigned short* dst;
    int i4;
    if (blk < 128)      { src = B_W; dst = BWb;  i4 = (blk - 96) * 256 + tid; }
    else if (blk < 192) { src = Wd1; dst = Wd1b; i4 = (blk - 128) * 256 + tid; }
    else                { src = Wd2; dst = Wd2b; i4 = (blk - 192) * 256 + tid; }
    float4 v = *(const float4*)&src[(size_t)i4 * 4];
    *(ushort4*)&dst[(size_t)i4 * 4] =
        make_ushort4(f2bf(v.x), f2bf(v.y), f2bf(v.z), f2bf(v.w));
  }
}

// ---------------------------------------------------------------------------
// extract u columns -> dense bf16 [65536][128]
// ---------------------------------------------------------------------------
__global__ __launch_bounds__(256) void extract_u(const float* __restrict__ in,
                                                 unsigned short* __restrict__ ubuf) {
  const int gid = blockIdx.x * 256 + threadIdx.x;
  const int row = gid >> 5;
  const int c = (gid & 31) * 4;
  float4 v = *(const float4*)&in[(size_t)row * INDIM + 256 + c];
  *(ushort4*)&ubuf[(size_t)row * 128 + c] =
      make_ushort4(f2bf(v.x), f2bf(v.y), f2bf(v.z), f2bf(v.w));
}

// ---------------------------------------------------------------------------
// Chunked-scan phase kernel v4 (fp32): A cached in registers (v3) +
// DPP-only 8-way reduce (no ds_swizzle: -256 DS ops/CU/step) +
// carry stride 292 (store banks 4(dg+le)%32 -> 2-way, was 8-way).
// Thread (w,lane): dg=lane&7 owns d-slice [dg*32,+32), le=lane>>3, e-quad
// e0=w*32+le*4; 512 threads x 128 VGPR = 64K = A, zero replication.
// ---------------------------------------------------------------------------
__global__ __launch_bounds__(512, 2) void phase_kernel(
    const float* __restrict__ AW, const float* __restrict__ Cbuf,
    const float* __restrict__ Einit, float* __restrict__ Lend,
    unsigned short* __restrict__ w1out) {
  const int tid = threadIdx.x;
  const int w = tid >> 6;
  const int lane = tid & 63;
  const int dg = lane & 7;        // d-group: owns d in [dg*32, dg*32+32)
  const int le = lane >> 3;       // e-quad within wave's 32-e slice
  const int e0 = w * 32 + le * 4;
  const int d0 = dg * 32;
  const int rho0 = blockIdx.x << 3;
  const int k = rho0 >> 5;
  const int b = (rho0 & 31) + dg;   // owned rho's batch index
  const int rho = rho0 + dg;        // owned rho (rho = k*32 + b)

  // carry[buf][rho][pd(d)], pd(d) = d + (d>>5)*4. Leading dim 292 so the
  // float4 store banks are 4*(dg+le)%32 -> 2-way (free); reads stay 8-bank.
  __shared__ __align__(16) float carry[2][8][292];

  // ---- load this thread's A tile into registers (once) ----
  float4 Ar[4][8];
#pragma unroll
  for (int i = 0; i < 4; ++i)
#pragma unroll
    for (int k4 = 0; k4 < 8; ++k4)
      Ar[i][k4] = *(const float4*)&AW[(size_t)(e0 + i) * 256 + d0 + k4 * 4];

  // ---- init carry[0]: thread initializes its owned (rho=dg, e-quad) ----
  float4 cur;
  if (Einit) cur = *(const float4*)&Einit[(size_t)rho * 256 + e0];
  else       cur = make_float4(0.f, 0.f, 0.f, 0.f);
  const int epad = e0 + ((e0 >> 5) << 2);   // = w*36 + le*4
  *(float4*)&carry[0][dg][epad] = cur;
  __syncthreads();

  const float4* crow = (const float4*)(Cbuf + ((size_t)b * TLEN + (size_t)k * CHL) * 256 + e0);
  ushort4* wrow = w1out
      ? (ushort4*)(w1out + ((size_t)b * TLEN + (size_t)k * CHL) * 256 + e0)
      : (ushort4*)0;

  int buf = 0;
  for (int j = 0; j < CHL; ++j) {
    float4 cj = *crow;  // independent of carry: latency hides under the FMAs
    crow += 64;
    float4 nxt = make_float4(0.f, 0.f, 0.f, 0.f);
#pragma unroll
    for (int r = 0; r < 8; ++r) {
      float4 s = make_float4(0.f, 0.f, 0.f, 0.f);
#pragma unroll
      for (int k4 = 0; k4 < 8; ++k4) {
        const float4 cv = *(const float4*)&carry[buf][r][dg * 36 + k4 * 4];
        s.x += Ar[0][k4].x * cv.x + Ar[0][k4].y * cv.y + Ar[0][k4].z * cv.z + Ar[0][k4].w * cv.w;
        s.y += Ar[1][k4].x * cv.x + Ar[1][k4].y * cv.y + Ar[1][k4].z * cv.z + Ar[1][k4].w * cv.w;
        s.z += Ar[2][k4].x * cv.x + Ar[2][k4].y * cv.y + Ar[2][k4].z * cv.z + Ar[2][k4].w * cv.w;
        s.w += Ar[3][k4].x * cv.x + Ar[3][k4].y * cv.y + Ar[3][k4].z * cv.z + Ar[3][k4].w * cv.w;
      }
      red8(s);                // all 8 dg lanes end with the full d-sum
      if (dg == r) nxt = s;   // stash the rho this thread owns
    }
    cur = make_float4(nxt.x + cj.x, nxt.y + cj.y, nxt.z + cj.z, nxt.w + cj.w);
    buf ^= 1;
    *(float4*)&carry[buf][dg][epad] = cur;
    if (w1out) {
      *wrow = make_ushort4(f2bf(ileakyf(cur.x)), f2bf(ileakyf(cur.y)),
                           f2bf(ileakyf(cur.z)), f2bf(ileakyf(cur.w)));
      wrow += 64;
    }
    __syncthreads();
  }
  if (Lend) *(float4*)&Lend[(size_t)rho * 256 + e0] = cur;
}

// ---------------------------------------------------------------------------
// Boundary recurrence v3: E[k+1] = P*E[k] + Lend[k], P = A^32 row-major.
// Same register-P structure as phase v4: thread (w,lane) holds
// P[e0..e0+3][dg*32..+32] in 128 VGPRs (zero replication across the block);
// per chunk only the 256-float E vector round-trips through padded LDS and
// the d-reduce is the DPP butterfly. Kills v2's per-chunk 256KB PT re-stream
// (the same disease phase v2 had).
// ---------------------------------------------------------------------------
__global__ __launch_bounds__(512, 2) void boundary_kernel(
    const float* __restrict__ P, const float* __restrict__ z0,
    const float* __restrict__ Lend, float* __restrict__ Earr) {
  const int tid = threadIdx.x;
  const int w = tid >> 6;
  const int lane = tid & 63;
  const int dg = lane & 7;
  const int le = lane >> 3;
  const int e0 = w * 32 + le * 4;
  const int d0 = dg * 32;
  const int b = blockIdx.x;

  __shared__ __align__(16) float Ec[292];  // padded: idx = x + (x>>5)*4

  float4 Pr[4][8];
#pragma unroll
  for (int i = 0; i < 4; ++i)
#pragma unroll
    for (int k4 = 0; k4 < 8; ++k4)
      Pr[i][k4] = *(const float4*)&P[(size_t)(e0 + i) * 256 + d0 + k4 * 4];

  float4 cur = *(const float4*)&z0[(size_t)b * 256 + e0];  // E[0] (all dg replicas)
  const int epad = e0 + ((e0 >> 5) << 2);
  if (dg == 0) *(float4*)&Ec[epad] = cur;
  __syncthreads();

  for (int k = 0; k < NCH; ++k) {
    // issue the Lend load early; it's consumed after the matvec
    const float4 lv = *(const float4*)&Lend[((size_t)k * BSZ + b) * 256 + e0];
    if (dg == 0) *(float4*)&Earr[((size_t)k * BSZ + b) * 256 + e0] = cur;

    float4 s = make_float4(0.f, 0.f, 0.f, 0.f);
#pragma unroll
    for (int k4 = 0; k4 < 8; ++k4) {
      const float4 cv = *(const float4*)&Ec[dg * 36 + k4 * 4];
      s.x += Pr[0][k4].x * cv.x + Pr[0][k4].y * cv.y + Pr[0][k4].z * cv.z + Pr[0][k4].w * cv.w;
      s.y += Pr[1][k4].x * cv.x + Pr[1][k4].y * cv.y + Pr[1][k4].z * cv.z + Pr[1][k4].w * cv.w;
      s.z += Pr[2][k4].x * cv.x + Pr[2][k4].y * cv.y + Pr[2][k4].z * cv.z + Pr[2][k4].w * cv.w;
      s.w += Pr[3][k4].x * cv.x + Pr[3][k4].y * cv.y + Pr[3][k4].z * cv.z + Pr[3][k4].w * cv.w;
    }
    red8(s);
    cur = make_float4(s.x + lv.x, s.y + lv.y, s.z + lv.z, s.w + lv.w);
    __syncthreads();               // all Ec reads done before overwrite
    if (dg == 0) *(float4*)&Ec[epad] = cur;
    __syncthreads();               // new Ec visible
  }
}

// ---------------------------------------------------------------------------
extern "C" void kernel_launch(void* const* d_in, const int* in_sizes, int n_in,
                              void* d_out, int out_size, void* d_ws, size_t ws_size,
                              hipStream_t stream) {
  const float* in  = (const float*)d_in[0];
  const float* We1 = (const float*)d_in[1];
  const float* be1 = (const float*)d_in[2];
  const float* We2 = (const float*)d_in[3];
  const float* be2 = (const float*)d_in[4];
  const float* A_W = (const float*)d_in[5];
  const float* A_b = (const float*)d_in[6];
  const float* B_W = (const float*)d_in[7];
  const float* B_b = (const float*)d_in[8];
  const float* Wd1 = (const float*)d_in[9];
  const float* bd1 = (const float*)d_in[10];
  const float* Wd2 = (const float*)d_in[11];
  const float* bd2 = (const float*)d_in[12];
  float* out = (float*)d_out;

  float* ws   = (float*)d_ws;
  float* Cbuf = ws;                    // 16,777,216 f
  float* AT   = Cbuf + 16777216;       // 65,536
  float* PT   = AT + 65536;            // 65,536
  float* Pa   = PT + 65536;            // 65,536
  float* PaT  = Pa + 65536;            // 65,536
  float* Pb   = PaT + 65536;           // 65,536
  float* PbT  = Pb + 65536;            // 65,536
  float* z0   = PbT + 65536;           // 8,192
  float* Lend = z0 + 8192;             // 524,288
  float* Earr = Lend + 524288;         // 524,288
  unsigned short* BWb  = (unsigned short*)(Earr + 524288);  // 32,768 us
  unsigned short* Wd1b = BWb + 32768;                       // 65,536 us
  unsigned short* Wd2b = Wd1b + 65536;                      // 65,536 us

  // d_out staging: [0,16MB) ubuf bf16; [16MB,48MB) w1 bf16; final fp32 overwrites
  unsigned short* ubuf = (unsigned short*)d_out;            // 65536x128 bf16
  unsigned short* w1   = ubuf + 8388608;                    // 65536x256 bf16
  unsigned short* w2   = (unsigned short*)Cbuf;             // 65536x256 bf16 (Cbuf dead after phase3)

  // prep: transpose + encoder + 3x f2bf fused (was 5 launches)
  prep_kernel<<<256, 256, 0, stream>>>(in, We1, be1, We2, be2, A_W, B_W, Wd1,
                                       Wd2, AT, z0, BWb, Wd1b, Wd2b);
  extract_u<<<8192, 256, 0, stream>>>(in, ubuf);

  // c_t = u @ B_W^T + B_b + A_b -> Cbuf (fp32)
  gemm_mfma<<<dim3(512, 2), 256, 0, stream>>>(ubuf, ALEN, BWb, A_b, B_b, 0, 0, Cbuf);

  // P = A^32 by repeated squaring, dual-output (X^2, (X^2)^T) per launch
  gemm_sq<<<dim3(4, 4), 256, 0, stream>>>(A_W, AT, Pa, PaT);   // A^2
  gemm_sq<<<dim3(4, 4), 256, 0, stream>>>(Pa, PaT, Pb, PbT);   // A^4
  gemm_sq<<<dim3(4, 4), 256, 0, stream>>>(Pb, PbT, Pa, PaT);   // A^8
  gemm_sq<<<dim3(4, 4), 256, 0, stream>>>(Pa, PaT, Pb, PbT);   // A^16
  gemm_sq<<<dim3(4, 4), 256, 0, stream>>>(Pb, PbT, Pa, PT);    // A^32 (Pa; PT unused now)

  phase_kernel<<<256, 512, 0, stream>>>(A_W, Cbuf, nullptr, Lend, nullptr);
  boundary_kernel<<<32, 512, 0, stream>>>(Pa, z0, Lend, Earr);
  phase_kernel<<<256, 512, 0, stream>>>(A_W, Cbuf, Earr, nullptr, w1);

  // dec1: w2 = bf16(inv_leaky(w1 @ Wd1^T + bd1))
  gemm_mfma<<<dim3(512, 2), 256, 0, stream>>>(w1, D256, Wd1b, bd1, nullptr, 1, 1, w2);
  // dec2: y = w2 @ Wd2^T + bd2 -> d_out (fp32)
  gemm_mfma<<<dim3(512, 2), 256, 0, stream>>>(w2, D256, Wd2b, bd2, nullptr, 0, 0, out);
}